// Round 3
// baseline (850.751 us; speedup 1.0000x reference)
//
#include <hip/hip_runtime.h>

// ---------------------------------------------------------------------------
// Cylindrical flow, R10 = R9 + 16-row spline sub-rounds for 4 blocks/CU.
//   R9 (316us): regs 76+48=124 (fits 4 waves/SIMD) but LDS 51.2KB/block caps
//   occupancy at 3 blocks/CU (33%). The 32-row spline scratch (32x97 f32/wave)
//   is what forces 51KB.
//   R10: spline runs twice on 16 rows (acc2[pt][rd] per sub-round) -> scratch
//   16x97/wave -> 26,240 B/block -> 4 blocks/CU, register-limited (124<=128,
//   launch_bounds (256,4), +4 headroom vs R8's -56). Knot phase split across
//   lane pairs (16 rows x {w,h} x 2 halves = 64 lanes) with ORDER-EXACT
//   cumsum handoff (upper half restarts serial chain from lower half's c15
//   via shfl_xor) -> every value bit-identical to R9; absmax must stay
//   exactly 0.03125. Spill tripwire: WRITE_SIZE >> 8 MB.
// ---------------------------------------------------------------------------

typedef _Float16 f16x8 __attribute__((ext_vector_type(8)));
typedef float    f32x4 __attribute__((ext_vector_type(4)));

#define TWO_PI_F  6.28318530717958647692f
#define MIN_SZ    1e-3f
#define MIN_D_F   1e-3f
#define DERIV_OFF 0.54132485461291810f   /* ln(e-1) */

__device__ __forceinline__ float softplus_f(float x) {
    return fmaxf(x, 0.f) + log1pf(__expf(-fabsf(x)));
}

// ---------------------------------------------------------------------------
// Prep: pack W1 (std A-fragment order) and W2 (K-permuted A-fragment order),
// each as hi/lo fp16 split.
// W1 frag (ht,kx): lane l, j: A[h = ht*16+(l&15)][k = kx*32+(l>>4)*8+j]
// W2 frag (pt,kb): lane l, j: A[p = pt*16+(l&15)][h = (2kb+(j>>2))*16+(l>>4)*4+(j&3)]
// ---------------------------------------------------------------------------
__global__ void flow_prep(const float* __restrict__ W1, const float* __restrict__ W2,
                          _Float16* __restrict__ w1h, _Float16* __restrict__ w1l,
                          _Float16* __restrict__ w2h, _Float16* __restrict__ w2l) {
    int i = blockIdx.x * 256 + threadIdx.x;
    if (i < 16384) {                       // w1: [16 ht][2 kx][64 l][8 j]
        int j = i & 7, l = (i >> 3) & 63, kx = (i >> 9) & 1, ht = i >> 10;
        int h = ht * 16 + (l & 15);
        int k = kx * 32 + (l >> 4) * 8 + j;
        float v = W1[k * 256 + h];         // W1 (64,256) row-major
        _Float16 hv = (_Float16)v;
        w1h[i] = hv;
        w1l[i] = (_Float16)(v - (float)hv);
    }
    int i2 = i - 16384;
    if (i2 >= 0 && i2 < 24576) {           // w2: [6 pt][8 kb][64 l][8 j], K-permuted
        int j = i2 & 7, l = (i2 >> 3) & 63, kb = (i2 >> 9) & 7, pt = i2 >> 12;
        int p = pt * 16 + (l & 15);
        int h = (2 * kb + (j >> 2)) * 16 + ((l >> 4) << 2) + (j & 3);
        float v = W2[h * 96 + p];          // W2 (256,96) row-major
        _Float16 hv = (_Float16)v;
        w2h[i2] = hv;
        w2l[i2] = (_Float16)(v - (float)hv);
    }
}

__global__ __launch_bounds__(256, 4) void flow_main(
    const float* __restrict__ theta, const float* __restrict__ xc,
    const float* __restrict__ b1g, const float* __restrict__ b2g,
    const float* __restrict__ etag,
    const _Float16* __restrict__ w1h, const _Float16* __restrict__ w1l,
    const _Float16* __restrict__ w2h, const _Float16* __restrict__ w2l,
    float* __restrict__ out, int Btot)
{
    __shared__ __align__(16) float sP[4 * 16 * 97];   // per-wave 16x97 scratch
    __shared__ float sB1[256];
    __shared__ float sB2[96];

    const int t   = threadIdx.x;
    const int wid = t >> 6;
    const int l   = t & 63;
    const int q   = l >> 4;
    const int lc  = l & 15;
    const long R0w = ((long)blockIdx.x * 4 + wid) * 32;   // 32 rows per wave

    if (t < 256) sB1[t] = b1g[t];
    if (t < 96)  sB2[t] = b2g[t];
    __syncthreads();                       // only barrier in the kernel
    const float ev = etag[0];

    // prefetch theta for both sub-rounds (lanes 0..15 hold their 2 rows)
    float th0 = 0.f, th1 = 0.f;
    if (l < 16) {
        th0 = theta[R0w + l];
        th1 = theta[R0w + 16 + l];
    }

    const f16x8* w1vh = (const f16x8*)w1h;
    const f16x8* w1vl = (const f16x8*)w1l;
    const f16x8* w2vh = (const f16x8*)w2h;
    const f16x8* w2vl = (const f16x8*)w2l;

    // ---- load x fragments for this wave's 32 rows (persistent, 32 regs) ----
    f16x8 xh[2][2], xl[2][2];
    #pragma unroll
    for (int mt = 0; mt < 2; ++mt)
        #pragma unroll
        for (int kx = 0; kx < 2; ++kx) {
            const float* xp = xc + (R0w + mt * 16 + lc) * 64 + kx * 32 + q * 8;
            float4 v0 = *(const float4*)xp;
            float4 v1 = *(const float4*)(xp + 4);
            f16x8 hi, lo;
            hi[0] = (_Float16)v0.x; lo[0] = (_Float16)(v0.x - (float)hi[0]);
            hi[1] = (_Float16)v0.y; lo[1] = (_Float16)(v0.y - (float)hi[1]);
            hi[2] = (_Float16)v0.z; lo[2] = (_Float16)(v0.z - (float)hi[2]);
            hi[3] = (_Float16)v0.w; lo[3] = (_Float16)(v0.w - (float)hi[3]);
            hi[4] = (_Float16)v1.x; lo[4] = (_Float16)(v1.x - (float)hi[4]);
            hi[5] = (_Float16)v1.y; lo[5] = (_Float16)(v1.y - (float)hi[5]);
            hi[6] = (_Float16)v1.z; lo[6] = (_Float16)(v1.z - (float)hi[6]);
            hi[7] = (_Float16)v1.w; lo[7] = (_Float16)(v1.w - (float)hi[7]);
            xh[mt][kx] = hi;
            xl[mt][kx] = lo;
        }

    // ---- fused K-loop: per kb, GEMM1 (2 h-tiles) -> relu/split -> GEMM2 ----
    f32x4 acc2[6][2] = {};                 // 48 regs (AGPR-eligible)
    #pragma unroll 2
    for (int kb = 0; kb < 8; ++kb) {
        f32x4 a1[2][2] = {};
        #pragma unroll
        for (int i = 0; i < 2; ++i) {
            const int ht = 2 * kb + i;
            #pragma unroll
            for (int kx = 0; kx < 2; ++kx) {
                f16x8 wh = w1vh[(ht * 2 + kx) * 64 + l];   // 1 KB coalesced (L2)
                f16x8 wl = w1vl[(ht * 2 + kx) * 64 + l];
                #pragma unroll
                for (int mt = 0; mt < 2; ++mt) {
                    a1[i][mt] = __builtin_amdgcn_mfma_f32_16x16x32_f16(wl, xh[mt][kx], a1[i][mt], 0, 0, 0);
                    a1[i][mt] = __builtin_amdgcn_mfma_f32_16x16x32_f16(wh, xl[mt][kx], a1[i][mt], 0, 0, 0);
                    a1[i][mt] = __builtin_amdgcn_mfma_f32_16x16x32_f16(wh, xh[mt][kx], a1[i][mt], 0, 0, 0);
                }
            }
        }
        // epilogue: bias+relu+split; GEMM1 C-layout IS GEMM2 B-frag (K-perm)
        f16x8 bh[2], bl[2];
        float4 bb0 = *(const float4*)(sB1 + (2 * kb + 0) * 16 + q * 4);
        float4 bb1 = *(const float4*)(sB1 + (2 * kb + 1) * 16 + q * 4);
        #pragma unroll
        for (int mt = 0; mt < 2; ++mt) {
            f16x8 hi, lo;
            float v;
            v = fmaxf(a1[0][mt][0] + bb0.x, 0.f); hi[0] = (_Float16)v; lo[0] = (_Float16)(v - (float)hi[0]);
            v = fmaxf(a1[0][mt][1] + bb0.y, 0.f); hi[1] = (_Float16)v; lo[1] = (_Float16)(v - (float)hi[1]);
            v = fmaxf(a1[0][mt][2] + bb0.z, 0.f); hi[2] = (_Float16)v; lo[2] = (_Float16)(v - (float)hi[2]);
            v = fmaxf(a1[0][mt][3] + bb0.w, 0.f); hi[3] = (_Float16)v; lo[3] = (_Float16)(v - (float)hi[3]);
            v = fmaxf(a1[1][mt][0] + bb1.x, 0.f); hi[4] = (_Float16)v; lo[4] = (_Float16)(v - (float)hi[4]);
            v = fmaxf(a1[1][mt][1] + bb1.y, 0.f); hi[5] = (_Float16)v; lo[5] = (_Float16)(v - (float)hi[5]);
            v = fmaxf(a1[1][mt][2] + bb1.z, 0.f); hi[6] = (_Float16)v; lo[6] = (_Float16)(v - (float)hi[6]);
            v = fmaxf(a1[1][mt][3] + bb1.w, 0.f); hi[7] = (_Float16)v; lo[7] = (_Float16)(v - (float)hi[7]);
            bh[mt] = hi;
            bl[mt] = lo;
        }
        #pragma unroll
        for (int pt = 0; pt < 6; ++pt) {
            f16x8 wh = w2vh[(pt * 8 + kb) * 64 + l];       // 1 KB coalesced (L2)
            f16x8 wl = w2vl[(pt * 8 + kb) * 64 + l];
            #pragma unroll
            for (int mt = 0; mt < 2; ++mt) {
                acc2[pt][mt] = __builtin_amdgcn_mfma_f32_16x16x32_f16(wl, bh[mt], acc2[pt][mt], 0, 0, 0);
                acc2[pt][mt] = __builtin_amdgcn_mfma_f32_16x16x32_f16(wh, bl[mt], acc2[pt][mt], 0, 0, 0);
                acc2[pt][mt] = __builtin_amdgcn_mfma_f32_16x16x32_f16(wh, bh[mt], acc2[pt][mt], 0, 0, 0);
            }
        }
    }

    // ---- spline: TWO sub-rounds of 16 rows, wave-private LDS, no barriers --
    // acc2[pt][rd] holds P[p][row = rd*16 + lc]; scratch is 16x97 per wave.
    float* sPw = sP + wid * (16 * 97);
    const int krow  = l & 15;          // knot row
    const int kset  = (l >> 4) & 1;    // 0 = widths (cols 0..31), 1 = heights (32..63)
    const int khalf = l >> 5;          // 0: entries 0..15, 1: entries 16..31

    #pragma unroll
    for (int rd = 0; rd < 2; ++rd) {
        // write P[r][p] = (acc2 + b2)*eta ; r = lc, p = pt*16+q*4
        #pragma unroll
        for (int pt = 0; pt < 6; ++pt) {
            float4 bb = *(const float4*)(sB2 + pt * 16 + q * 4);
            f32x4 v = acc2[pt][rd];
            float* dst = sPw + lc * 97 + pt * 16 + q * 4;
            dst[0] = (v[0] + bb.x) * ev;
            dst[1] = (v[1] + bb.y) * ev;
            dst[2] = (v[2] + bb.z) * ev;
            dst[3] = (v[3] + bb.w) * ev;
        }
        // knots: 64 lanes = 16 rows x {w,h} x 2 halves. Order-exact split:
        //   max: tree (fmax exactly associative -> bit-identical)
        //   cumsum: upper half restarts serial chain from lower half's c15
        //   S = upper half's final c (exact reference association)
        {
            float* basep = sPw + krow * 97 + kset * 32 + khalf * 16;
            float tv[16];
            #pragma unroll
            for (int j = 0; j < 16; ++j) tv[j] = basep[j];
            float mx = tv[0];
            #pragma unroll
            for (int j = 1; j < 16; ++j) mx = fmaxf(mx, tv[j]);
            mx = fmaxf(mx, __shfl_xor(mx, 32));
            // exps + local serial sum (half0's sum == exact c15)
            float cl = 0.f;
            #pragma unroll
            for (int j = 0; j < 16; ++j) {
                tv[j] = __expf(tv[j] - mx);
                cl += tv[j];
            }
            float cpart = __shfl_xor(cl, 32);      // half1 receives half0's c15
            // serial cumsum, order-exact: half0 from 0, half1 from c15
            float c = khalf ? cpart : 0.f;
            #pragma unroll
            for (int j = 0; j < 16; ++j) {
                c += tv[j];
                tv[j] = c;
            }
            float Sx = __shfl_xor(c, 32);          // half0 receives half1's c31 (=S)
            float S = khalf ? c : Sx;
            float scale = (1.0f - 32.0f * MIN_SZ) / S;
            float base_off = MIN_SZ * (float)(khalf * 16 + 1);
            #pragma unroll
            for (int j = 0; j < 16; ++j)
                basep[j] = TWO_PI_F * fmaf(scale, tv[j], base_off + MIN_SZ * (float)j);
            if (khalf) basep[15] = TWO_PI_F;       // knot_32 = right boundary
        }
        // eval + store: lanes 0..15 (one per row)
        if (l < 16) {
            const float* row = sPw + l * 97;
            long gr = R0w + rd * 16 + l;
            float th_in = rd ? th1 : th0;
            int bin = 0;
            #pragma unroll
            for (int j = 0; j < 32; ++j) bin += (th_in >= row[j]) ? 1 : 0;
            bin = min(bin, 31);

            float cwk1 = row[bin];
            float cwk0 = (bin == 0) ? 0.f : row[bin - 1];
            float chk1 = row[32 + bin];
            float chk0 = (bin == 0) ? 0.f : row[32 + bin - 1];
            float in_w = cwk1 - cwk0;
            float in_h = chk1 - chk0;
            float d_k  = MIN_D_F + softplus_f(row[64 + bin] + DERIV_OFF);
            float d_k1 = MIN_D_F + softplus_f(row[64 + ((bin + 1) & 31)] + DERIV_OFF);

            float s   = in_h / in_w;
            float tt  = (th_in - cwk0) / in_w;
            float tom = tt * (1.f - tt);
            float denom = s + (d_k1 + d_k - 2.f * s) * tom;
            float numer = in_h * (s * tt * tt + d_k * tom);
            float outv  = chk0 + numer / denom;
            float omt   = 1.f - tt;
            float dnum  = s * s * (d_k1 * tt * tt + 2.f * s * tom + d_k * omt * omt);
            float lad   = __logf(dnum) - 2.f * __logf(denom);

            out[gr]               = outv;
            out[(long)Btot + gr]  = lad;
        }
    }
}

extern "C" void kernel_launch(void* const* d_in, const int* in_sizes, int n_in,
                              void* d_out, int out_size, void* d_ws, size_t ws_size,
                              hipStream_t stream) {
    const float* theta = (const float*)d_in[0];
    const float* xcond = (const float*)d_in[1];
    const float* W1    = (const float*)d_in[2];
    const float* b1    = (const float*)d_in[3];
    const float* W2    = (const float*)d_in[4];
    const float* b2    = (const float*)d_in[5];
    const float* eta   = (const float*)d_in[6];
    int Btot = in_sizes[0];                    // 1048576 (d = 1)

    _Float16* w1h = (_Float16*)d_ws;           // 16384 f16
    _Float16* w1l = w1h + 16384;
    _Float16* w2h = w1l + 16384;               // 24576 f16
    _Float16* w2l = w2h + 24576;               // total 160 KiB of ws

    flow_prep<<<160, 256, 0, stream>>>(W1, W2, w1h, w1l, w2h, w2l);
    // 32 rows per wave, 4 waves per block -> 128 rows/block
    flow_main<<<Btot / 128, 256, 0, stream>>>(theta, xcond, b1, b2, eta,
                                              w1h, w1l, w2h, w2l,
                                              (float*)d_out, Btot);
}

// Round 4
// 814.414 us; speedup vs baseline: 1.0446x; 1.0446x over previous
//
#include <hip/hip_runtime.h>

// ---------------------------------------------------------------------------
// Cylindrical flow, R11 = R10 + xl-in-LDS to fit the 64-reg arch partition.
//   R9  (316us): 76 arch + 48 AGPR, LDS 51KB -> 3 blocks/CU, latency-bound.
//   R10 (615us): 16-row spline sub-rounds got LDS to 26.6KB (4 blocks/CU) but
//     (256,4) forces a 64/64 arch/AGPR split; arch live ~76 > 64 -> ~12 regs
//     spilled in the kb loop -> 890MB WRITE_SIZE, MfmaUtil 17.7.
//   R11: move the persistent x lo-residuals (16 VGPRs) into the first 4KB of
//   the wave's spline scratch (wave-private, time-shared: xl dead before sPw
//   is written; same-wave LDS program order makes it safe, no barrier).
//   GEMM1 reordered kx-outer so only 2 xl frags (8 regs) are live at once.
//   Arch live ~56-60 <= 64; AGPR 48 (+16 transient a1) <= 64. LDS unchanged
//   26,624 -> still 4 blocks/CU. Spline phase identical to R10 (bit-exact,
//   absmax 0.03125). Spill tripwire: WRITE_SIZE >> 8 MB.
// ---------------------------------------------------------------------------

typedef _Float16 f16x8 __attribute__((ext_vector_type(8)));
typedef float    f32x4 __attribute__((ext_vector_type(4)));

#define TWO_PI_F  6.28318530717958647692f
#define MIN_SZ    1e-3f
#define MIN_D_F   1e-3f
#define DERIV_OFF 0.54132485461291810f   /* ln(e-1) */

__device__ __forceinline__ float softplus_f(float x) {
    return fmaxf(x, 0.f) + log1pf(__expf(-fabsf(x)));
}

// ---------------------------------------------------------------------------
// Prep: pack W1 (std A-fragment order) and W2 (K-permuted A-fragment order),
// each as hi/lo fp16 split.
// W1 frag (ht,kx): lane l, j: A[h = ht*16+(l&15)][k = kx*32+(l>>4)*8+j]
// W2 frag (pt,kb): lane l, j: A[p = pt*16+(l&15)][h = (2kb+(j>>2))*16+(l>>4)*4+(j&3)]
// ---------------------------------------------------------------------------
__global__ void flow_prep(const float* __restrict__ W1, const float* __restrict__ W2,
                          _Float16* __restrict__ w1h, _Float16* __restrict__ w1l,
                          _Float16* __restrict__ w2h, _Float16* __restrict__ w2l) {
    int i = blockIdx.x * 256 + threadIdx.x;
    if (i < 16384) {                       // w1: [16 ht][2 kx][64 l][8 j]
        int j = i & 7, l = (i >> 3) & 63, kx = (i >> 9) & 1, ht = i >> 10;
        int h = ht * 16 + (l & 15);
        int k = kx * 32 + (l >> 4) * 8 + j;
        float v = W1[k * 256 + h];         // W1 (64,256) row-major
        _Float16 hv = (_Float16)v;
        w1h[i] = hv;
        w1l[i] = (_Float16)(v - (float)hv);
    }
    int i2 = i - 16384;
    if (i2 >= 0 && i2 < 24576) {           // w2: [6 pt][8 kb][64 l][8 j], K-permuted
        int j = i2 & 7, l = (i2 >> 3) & 63, kb = (i2 >> 9) & 7, pt = i2 >> 12;
        int p = pt * 16 + (l & 15);
        int h = (2 * kb + (j >> 2)) * 16 + ((l >> 4) << 2) + (j & 3);
        float v = W2[h * 96 + p];          // W2 (256,96) row-major
        _Float16 hv = (_Float16)v;
        w2h[i2] = hv;
        w2l[i2] = (_Float16)(v - (float)hv);
    }
}

__global__ __launch_bounds__(256, 4) void flow_main(
    const float* __restrict__ theta, const float* __restrict__ xc,
    const float* __restrict__ b1g, const float* __restrict__ b2g,
    const float* __restrict__ etag,
    const _Float16* __restrict__ w1h, const _Float16* __restrict__ w1l,
    const _Float16* __restrict__ w2h, const _Float16* __restrict__ w2l,
    float* __restrict__ out, int Btot)
{
    __shared__ __align__(16) float sP[4 * 16 * 97];   // per-wave 16x97 scratch
    __shared__ float sB1[256];
    __shared__ float sB2[96];

    const int t   = threadIdx.x;
    const int wid = t >> 6;
    const int l   = t & 63;
    const int q   = l >> 4;
    const int lc  = l & 15;
    const long R0w = ((long)blockIdx.x * 4 + wid) * 32;   // 32 rows per wave

    if (t < 256) sB1[t] = b1g[t];
    if (t < 96)  sB2[t] = b2g[t];
    __syncthreads();                       // only barrier in the kernel
    const float ev = etag[0];

    // per-wave spline scratch; its first 4KB time-shares as xl staging
    float* sPw = sP + wid * (16 * 97);
    f16x8* xlw = (f16x8*)sPw;              // [mt*2+kx][lane] f16x8, 4KB

    // prefetch theta for both sub-rounds (lanes 0..15 hold their 2 rows)
    float th0 = 0.f, th1 = 0.f;
    if (l < 16) {
        th0 = theta[R0w + l];
        th1 = theta[R0w + 16 + l];
    }

    const f16x8* w1vh = (const f16x8*)w1h;
    const f16x8* w1vl = (const f16x8*)w1l;
    const f16x8* w2vh = (const f16x8*)w2h;
    const f16x8* w2vl = (const f16x8*)w2l;

    // ---- load x fragments: hi in regs (16 VGPR), lo to wave-private LDS ----
    f16x8 xh[2][2];
    #pragma unroll
    for (int mt = 0; mt < 2; ++mt)
        #pragma unroll
        for (int kx = 0; kx < 2; ++kx) {
            const float* xp = xc + (R0w + mt * 16 + lc) * 64 + kx * 32 + q * 8;
            float4 v0 = *(const float4*)xp;
            float4 v1 = *(const float4*)(xp + 4);
            f16x8 hi, lo;
            hi[0] = (_Float16)v0.x; lo[0] = (_Float16)(v0.x - (float)hi[0]);
            hi[1] = (_Float16)v0.y; lo[1] = (_Float16)(v0.y - (float)hi[1]);
            hi[2] = (_Float16)v0.z; lo[2] = (_Float16)(v0.z - (float)hi[2]);
            hi[3] = (_Float16)v0.w; lo[3] = (_Float16)(v0.w - (float)hi[3]);
            hi[4] = (_Float16)v1.x; lo[4] = (_Float16)(v1.x - (float)hi[4]);
            hi[5] = (_Float16)v1.y; lo[5] = (_Float16)(v1.y - (float)hi[5]);
            hi[6] = (_Float16)v1.z; lo[6] = (_Float16)(v1.z - (float)hi[6]);
            hi[7] = (_Float16)v1.w; lo[7] = (_Float16)(v1.w - (float)hi[7]);
            xh[mt][kx] = hi;
            xlw[(mt * 2 + kx) * 64 + l] = lo;
        }

    // ---- fused K-loop: per kb, GEMM1 (2 h-tiles) -> relu/split -> GEMM2 ----
    f32x4 acc2[6][2] = {};                 // 48 regs (AGPR side)
    #pragma unroll 2
    for (int kb = 0; kb < 8; ++kb) {
        f32x4 a1[2][2] = {};
        #pragma unroll
        for (int kx = 0; kx < 2; ++kx) {   // kx OUTER: only 2 xl frags live
            f16x8 xl0 = xlw[(0 * 2 + kx) * 64 + l];
            f16x8 xl1 = xlw[(1 * 2 + kx) * 64 + l];
            #pragma unroll
            for (int i = 0; i < 2; ++i) {
                const int ht = 2 * kb + i;
                f16x8 wh = w1vh[(ht * 2 + kx) * 64 + l];   // 1 KB coalesced (L2)
                f16x8 wl = w1vl[(ht * 2 + kx) * 64 + l];
                a1[i][0] = __builtin_amdgcn_mfma_f32_16x16x32_f16(wl, xh[0][kx], a1[i][0], 0, 0, 0);
                a1[i][0] = __builtin_amdgcn_mfma_f32_16x16x32_f16(wh, xl0,       a1[i][0], 0, 0, 0);
                a1[i][0] = __builtin_amdgcn_mfma_f32_16x16x32_f16(wh, xh[0][kx], a1[i][0], 0, 0, 0);
                a1[i][1] = __builtin_amdgcn_mfma_f32_16x16x32_f16(wl, xh[1][kx], a1[i][1], 0, 0, 0);
                a1[i][1] = __builtin_amdgcn_mfma_f32_16x16x32_f16(wh, xl1,       a1[i][1], 0, 0, 0);
                a1[i][1] = __builtin_amdgcn_mfma_f32_16x16x32_f16(wh, xh[1][kx], a1[i][1], 0, 0, 0);
            }
        }
        // epilogue: bias+relu+split; GEMM1 C-layout IS GEMM2 B-frag (K-perm)
        f16x8 bh[2], bl[2];
        float4 bb0 = *(const float4*)(sB1 + (2 * kb + 0) * 16 + q * 4);
        float4 bb1 = *(const float4*)(sB1 + (2 * kb + 1) * 16 + q * 4);
        #pragma unroll
        for (int mt = 0; mt < 2; ++mt) {
            f16x8 hi, lo;
            float v;
            v = fmaxf(a1[0][mt][0] + bb0.x, 0.f); hi[0] = (_Float16)v; lo[0] = (_Float16)(v - (float)hi[0]);
            v = fmaxf(a1[0][mt][1] + bb0.y, 0.f); hi[1] = (_Float16)v; lo[1] = (_Float16)(v - (float)hi[1]);
            v = fmaxf(a1[0][mt][2] + bb0.z, 0.f); hi[2] = (_Float16)v; lo[2] = (_Float16)(v - (float)hi[2]);
            v = fmaxf(a1[0][mt][3] + bb0.w, 0.f); hi[3] = (_Float16)v; lo[3] = (_Float16)(v - (float)hi[3]);
            v = fmaxf(a1[1][mt][0] + bb1.x, 0.f); hi[4] = (_Float16)v; lo[4] = (_Float16)(v - (float)hi[4]);
            v = fmaxf(a1[1][mt][1] + bb1.y, 0.f); hi[5] = (_Float16)v; lo[5] = (_Float16)(v - (float)hi[5]);
            v = fmaxf(a1[1][mt][2] + bb1.z, 0.f); hi[6] = (_Float16)v; lo[6] = (_Float16)(v - (float)hi[6]);
            v = fmaxf(a1[1][mt][3] + bb1.w, 0.f); hi[7] = (_Float16)v; lo[7] = (_Float16)(v - (float)hi[7]);
            bh[mt] = hi;
            bl[mt] = lo;
        }
        #pragma unroll
        for (int pt = 0; pt < 6; ++pt) {
            f16x8 wh = w2vh[(pt * 8 + kb) * 64 + l];       // 1 KB coalesced (L2)
            f16x8 wl = w2vl[(pt * 8 + kb) * 64 + l];
            #pragma unroll
            for (int mt = 0; mt < 2; ++mt) {
                acc2[pt][mt] = __builtin_amdgcn_mfma_f32_16x16x32_f16(wl, bh[mt], acc2[pt][mt], 0, 0, 0);
                acc2[pt][mt] = __builtin_amdgcn_mfma_f32_16x16x32_f16(wh, bl[mt], acc2[pt][mt], 0, 0, 0);
                acc2[pt][mt] = __builtin_amdgcn_mfma_f32_16x16x32_f16(wh, bh[mt], acc2[pt][mt], 0, 0, 0);
            }
        }
    }

    // ---- spline: TWO sub-rounds of 16 rows, wave-private LDS, no barriers --
    // acc2[pt][rd] holds P[p][row = rd*16 + lc]; scratch is 16x97 per wave.
    // (first sub-round's P-writes overwrite the dead xl staging region)
    const int krow  = l & 15;          // knot row
    const int kset  = (l >> 4) & 1;    // 0 = widths (cols 0..31), 1 = heights (32..63)
    const int khalf = l >> 5;          // 0: entries 0..15, 1: entries 16..31

    #pragma unroll
    for (int rd = 0; rd < 2; ++rd) {
        // write P[r][p] = (acc2 + b2)*eta ; r = lc, p = pt*16+q*4
        #pragma unroll
        for (int pt = 0; pt < 6; ++pt) {
            float4 bb = *(const float4*)(sB2 + pt * 16 + q * 4);
            f32x4 v = acc2[pt][rd];
            float* dst = sPw + lc * 97 + pt * 16 + q * 4;
            dst[0] = (v[0] + bb.x) * ev;
            dst[1] = (v[1] + bb.y) * ev;
            dst[2] = (v[2] + bb.z) * ev;
            dst[3] = (v[3] + bb.w) * ev;
        }
        // knots: 64 lanes = 16 rows x {w,h} x 2 halves. Order-exact split:
        //   max: tree (fmax exactly associative -> bit-identical)
        //   cumsum: upper half restarts serial chain from lower half's c15
        //   S = upper half's final c (exact reference association)
        {
            float* basep = sPw + krow * 97 + kset * 32 + khalf * 16;
            float tv[16];
            #pragma unroll
            for (int j = 0; j < 16; ++j) tv[j] = basep[j];
            float mx = tv[0];
            #pragma unroll
            for (int j = 1; j < 16; ++j) mx = fmaxf(mx, tv[j]);
            mx = fmaxf(mx, __shfl_xor(mx, 32));
            // exps + local serial sum (half0's sum == exact c15)
            float cl = 0.f;
            #pragma unroll
            for (int j = 0; j < 16; ++j) {
                tv[j] = __expf(tv[j] - mx);
                cl += tv[j];
            }
            float cpart = __shfl_xor(cl, 32);      // half1 receives half0's c15
            // serial cumsum, order-exact: half0 from 0, half1 from c15
            float c = khalf ? cpart : 0.f;
            #pragma unroll
            for (int j = 0; j < 16; ++j) {
                c += tv[j];
                tv[j] = c;
            }
            float Sx = __shfl_xor(c, 32);          // half0 receives half1's c31 (=S)
            float S = khalf ? c : Sx;
            float scale = (1.0f - 32.0f * MIN_SZ) / S;
            float base_off = MIN_SZ * (float)(khalf * 16 + 1);
            #pragma unroll
            for (int j = 0; j < 16; ++j)
                basep[j] = TWO_PI_F * fmaf(scale, tv[j], base_off + MIN_SZ * (float)j);
            if (khalf) basep[15] = TWO_PI_F;       // knot_32 = right boundary
        }
        // eval + store: lanes 0..15 (one per row)
        if (l < 16) {
            const float* row = sPw + l * 97;
            long gr = R0w + rd * 16 + l;
            float th_in = rd ? th1 : th0;
            int bin = 0;
            #pragma unroll
            for (int j = 0; j < 32; ++j) bin += (th_in >= row[j]) ? 1 : 0;
            bin = min(bin, 31);

            float cwk1 = row[bin];
            float cwk0 = (bin == 0) ? 0.f : row[bin - 1];
            float chk1 = row[32 + bin];
            float chk0 = (bin == 0) ? 0.f : row[32 + bin - 1];
            float in_w = cwk1 - cwk0;
            float in_h = chk1 - chk0;
            float d_k  = MIN_D_F + softplus_f(row[64 + bin] + DERIV_OFF);
            float d_k1 = MIN_D_F + softplus_f(row[64 + ((bin + 1) & 31)] + DERIV_OFF);

            float s   = in_h / in_w;
            float tt  = (th_in - cwk0) / in_w;
            float tom = tt * (1.f - tt);
            float denom = s + (d_k1 + d_k - 2.f * s) * tom;
            float numer = in_h * (s * tt * tt + d_k * tom);
            float outv  = chk0 + numer / denom;
            float omt   = 1.f - tt;
            float dnum  = s * s * (d_k1 * tt * tt + 2.f * s * tom + d_k * omt * omt);
            float lad   = __logf(dnum) - 2.f * __logf(denom);

            out[gr]               = outv;
            out[(long)Btot + gr]  = lad;
        }
    }
}

extern "C" void kernel_launch(void* const* d_in, const int* in_sizes, int n_in,
                              void* d_out, int out_size, void* d_ws, size_t ws_size,
                              hipStream_t stream) {
    const float* theta = (const float*)d_in[0];
    const float* xcond = (const float*)d_in[1];
    const float* W1    = (const float*)d_in[2];
    const float* b1    = (const float*)d_in[3];
    const float* W2    = (const float*)d_in[4];
    const float* b2    = (const float*)d_in[5];
    const float* eta   = (const float*)d_in[6];
    int Btot = in_sizes[0];                    // 1048576 (d = 1)

    _Float16* w1h = (_Float16*)d_ws;           // 16384 f16
    _Float16* w1l = w1h + 16384;
    _Float16* w2h = w1l + 16384;               // 24576 f16
    _Float16* w2l = w2h + 24576;               // total 160 KiB of ws

    flow_prep<<<160, 256, 0, stream>>>(W1, W2, w1h, w1l, w2h, w2l);
    // 32 rows per wave, 4 waves per block -> 128 rows/block
    flow_main<<<Btot / 128, 256, 0, stream>>>(theta, xcond, b1, b2, eta,
                                              w1h, w1l, w2h, w2l,
                                              (float*)d_out, Btot);
}

// Round 5
// 586.752 us; speedup vs baseline: 1.4499x; 1.3880x over previous
//
#include <hip/hip_runtime.h>

// ---------------------------------------------------------------------------
// Cylindrical flow, R12 = R11 + xh-in-LDS + kb-unroll-1 to truly fit 64 arch.
//   R9  (316us): 76 arch + 64 AGPR = 140 total -> 3 waves/SIMD (LDS also 3).
//   R10 (615us): (256,4) forces 64/64 split, arch demand ~80 -> 890MB spill.
//   R11 (578us): xl->LDS cut demand ~16 -> 757MB spill. Mechanism confirmed,
//     magnitude insufficient: xh[2][2] (16 regs) + unroll-2 load hoisting
//     (~8-16 transients) keep arch demand ~75-85 > 64.
//   R12: xh ALSO staged in wave-private LDS (8KB staging region, union'd with
//   the 6.2KB spline scratch -> 8KB/wave, ~34KB/block, still 4 blocks/CU) and
//   kb loop unroll 1 (halves in-flight weight loads). Peak arch live ~50-58
//   <= 64; AGPR = a1 16 + acc2 48 = 64. Spline = R10's bit-exact version.
//   Tripwire: WRITE_SIZE >> 8MB means the allocator floor is >64 arch ->
//   fall back to (256,3) with this body.
// ---------------------------------------------------------------------------

typedef _Float16 f16x8 __attribute__((ext_vector_type(8)));
typedef float    f32x4 __attribute__((ext_vector_type(4)));

#define TWO_PI_F  6.28318530717958647692f
#define MIN_SZ    1e-3f
#define MIN_D_F   1e-3f
#define DERIV_OFF 0.54132485461291810f   /* ln(e-1) */

__device__ __forceinline__ float softplus_f(float x) {
    return fmaxf(x, 0.f) + log1pf(__expf(-fabsf(x)));
}

// ---------------------------------------------------------------------------
// Prep: pack W1 (std A-fragment order) and W2 (K-permuted A-fragment order),
// each as hi/lo fp16 split.
// W1 frag (ht,kx): lane l, j: A[h = ht*16+(l&15)][k = kx*32+(l>>4)*8+j]
// W2 frag (pt,kb): lane l, j: A[p = pt*16+(l&15)][h = (2kb+(j>>2))*16+(l>>4)*4+(j&3)]
// ---------------------------------------------------------------------------
__global__ void flow_prep(const float* __restrict__ W1, const float* __restrict__ W2,
                          _Float16* __restrict__ w1h, _Float16* __restrict__ w1l,
                          _Float16* __restrict__ w2h, _Float16* __restrict__ w2l) {
    int i = blockIdx.x * 256 + threadIdx.x;
    if (i < 16384) {                       // w1: [16 ht][2 kx][64 l][8 j]
        int j = i & 7, l = (i >> 3) & 63, kx = (i >> 9) & 1, ht = i >> 10;
        int h = ht * 16 + (l & 15);
        int k = kx * 32 + (l >> 4) * 8 + j;
        float v = W1[k * 256 + h];         // W1 (64,256) row-major
        _Float16 hv = (_Float16)v;
        w1h[i] = hv;
        w1l[i] = (_Float16)(v - (float)hv);
    }
    int i2 = i - 16384;
    if (i2 >= 0 && i2 < 24576) {           // w2: [6 pt][8 kb][64 l][8 j], K-permuted
        int j = i2 & 7, l = (i2 >> 3) & 63, kb = (i2 >> 9) & 7, pt = i2 >> 12;
        int p = pt * 16 + (l & 15);
        int h = (2 * kb + (j >> 2)) * 16 + ((l >> 4) << 2) + (j & 3);
        float v = W2[h * 96 + p];          // W2 (256,96) row-major
        _Float16 hv = (_Float16)v;
        w2h[i2] = hv;
        w2l[i2] = (_Float16)(v - (float)hv);
    }
}

__global__ __launch_bounds__(256, 4) void flow_main(
    const float* __restrict__ theta, const float* __restrict__ xc,
    const float* __restrict__ b1g, const float* __restrict__ b2g,
    const float* __restrict__ etag,
    const _Float16* __restrict__ w1h, const _Float16* __restrict__ w1l,
    const _Float16* __restrict__ w2h, const _Float16* __restrict__ w2l,
    float* __restrict__ out, int Btot)
{
    // per-wave 8KB scratch: [0,4KB) xh staging, [4KB,8KB) xl staging during
    // the GEMM phase; reused as the 16x97 f32 spline scratch afterwards.
    __shared__ __align__(16) float sP[4 * 2048];
    __shared__ float sB1[256];
    __shared__ float sB2[96];

    const int t   = threadIdx.x;
    const int wid = t >> 6;
    const int l   = t & 63;
    const int q   = l >> 4;
    const int lc  = l & 15;
    const long R0w = ((long)blockIdx.x * 4 + wid) * 32;   // 32 rows per wave

    if (t < 256) sB1[t] = b1g[t];
    if (t < 96)  sB2[t] = b2g[t];
    __syncthreads();                       // only barrier in the kernel
    const float ev = etag[0];

    float* sPw = sP + wid * 2048;
    f16x8* xhw = (f16x8*)sPw;              // [mt*2+kx][lane] f16x8, 4KB
    f16x8* xlw = (f16x8*)(sPw + 1024);     // [mt*2+kx][lane] f16x8, 4KB

    // prefetch theta for both sub-rounds (lanes 0..15 hold their 2 rows)
    float th0 = 0.f, th1 = 0.f;
    if (l < 16) {
        th0 = theta[R0w + l];
        th1 = theta[R0w + 16 + l];
    }

    const f16x8* w1vh = (const f16x8*)w1h;
    const f16x8* w1vl = (const f16x8*)w1l;
    const f16x8* w2vh = (const f16x8*)w2h;
    const f16x8* w2vl = (const f16x8*)w2l;

    // ---- load x fragments: hi AND lo staged to wave-private LDS ------------
    #pragma unroll
    for (int mt = 0; mt < 2; ++mt)
        #pragma unroll
        for (int kx = 0; kx < 2; ++kx) {
            const float* xp = xc + (R0w + mt * 16 + lc) * 64 + kx * 32 + q * 8;
            float4 v0 = *(const float4*)xp;
            float4 v1 = *(const float4*)(xp + 4);
            f16x8 hi, lo;
            hi[0] = (_Float16)v0.x; lo[0] = (_Float16)(v0.x - (float)hi[0]);
            hi[1] = (_Float16)v0.y; lo[1] = (_Float16)(v0.y - (float)hi[1]);
            hi[2] = (_Float16)v0.z; lo[2] = (_Float16)(v0.z - (float)hi[2]);
            hi[3] = (_Float16)v0.w; lo[3] = (_Float16)(v0.w - (float)hi[3]);
            hi[4] = (_Float16)v1.x; lo[4] = (_Float16)(v1.x - (float)hi[4]);
            hi[5] = (_Float16)v1.y; lo[5] = (_Float16)(v1.y - (float)hi[5]);
            hi[6] = (_Float16)v1.z; lo[6] = (_Float16)(v1.z - (float)hi[6]);
            hi[7] = (_Float16)v1.w; lo[7] = (_Float16)(v1.w - (float)hi[7]);
            xhw[(mt * 2 + kx) * 64 + l] = hi;
            xlw[(mt * 2 + kx) * 64 + l] = lo;
        }

    // ---- fused K-loop: per kb, GEMM1 (2 h-tiles) -> relu/split -> GEMM2 ----
    f32x4 acc2[6][2] = {};                 // 48 regs (AGPR side)
    #pragma unroll 1
    for (int kb = 0; kb < 8; ++kb) {
        f32x4 a1[2][2] = {};
        #pragma unroll
        for (int kx = 0; kx < 2; ++kx) {   // kx outer: 4 x-frags (16 regs) live
            f16x8 xh0 = xhw[(0 * 2 + kx) * 64 + l];
            f16x8 xh1 = xhw[(1 * 2 + kx) * 64 + l];
            f16x8 xl0 = xlw[(0 * 2 + kx) * 64 + l];
            f16x8 xl1 = xlw[(1 * 2 + kx) * 64 + l];
            #pragma unroll
            for (int i = 0; i < 2; ++i) {
                const int ht = 2 * kb + i;
                f16x8 wh = w1vh[(ht * 2 + kx) * 64 + l];   // 1 KB coalesced (L2)
                f16x8 wl = w1vl[(ht * 2 + kx) * 64 + l];
                a1[i][0] = __builtin_amdgcn_mfma_f32_16x16x32_f16(wl, xh0, a1[i][0], 0, 0, 0);
                a1[i][0] = __builtin_amdgcn_mfma_f32_16x16x32_f16(wh, xl0, a1[i][0], 0, 0, 0);
                a1[i][0] = __builtin_amdgcn_mfma_f32_16x16x32_f16(wh, xh0, a1[i][0], 0, 0, 0);
                a1[i][1] = __builtin_amdgcn_mfma_f32_16x16x32_f16(wl, xh1, a1[i][1], 0, 0, 0);
                a1[i][1] = __builtin_amdgcn_mfma_f32_16x16x32_f16(wh, xl1, a1[i][1], 0, 0, 0);
                a1[i][1] = __builtin_amdgcn_mfma_f32_16x16x32_f16(wh, xh1, a1[i][1], 0, 0, 0);
            }
        }
        // epilogue: bias+relu+split; GEMM1 C-layout IS GEMM2 B-frag (K-perm)
        f16x8 bh[2], bl[2];
        float4 bb0 = *(const float4*)(sB1 + (2 * kb + 0) * 16 + q * 4);
        float4 bb1 = *(const float4*)(sB1 + (2 * kb + 1) * 16 + q * 4);
        #pragma unroll
        for (int mt = 0; mt < 2; ++mt) {
            f16x8 hi, lo;
            float v;
            v = fmaxf(a1[0][mt][0] + bb0.x, 0.f); hi[0] = (_Float16)v; lo[0] = (_Float16)(v - (float)hi[0]);
            v = fmaxf(a1[0][mt][1] + bb0.y, 0.f); hi[1] = (_Float16)v; lo[1] = (_Float16)(v - (float)hi[1]);
            v = fmaxf(a1[0][mt][2] + bb0.z, 0.f); hi[2] = (_Float16)v; lo[2] = (_Float16)(v - (float)hi[2]);
            v = fmaxf(a1[0][mt][3] + bb0.w, 0.f); hi[3] = (_Float16)v; lo[3] = (_Float16)(v - (float)hi[3]);
            v = fmaxf(a1[1][mt][0] + bb1.x, 0.f); hi[4] = (_Float16)v; lo[4] = (_Float16)(v - (float)hi[4]);
            v = fmaxf(a1[1][mt][1] + bb1.y, 0.f); hi[5] = (_Float16)v; lo[5] = (_Float16)(v - (float)hi[5]);
            v = fmaxf(a1[1][mt][2] + bb1.z, 0.f); hi[6] = (_Float16)v; lo[6] = (_Float16)(v - (float)hi[6]);
            v = fmaxf(a1[1][mt][3] + bb1.w, 0.f); hi[7] = (_Float16)v; lo[7] = (_Float16)(v - (float)hi[7]);
            bh[mt] = hi;
            bl[mt] = lo;
        }
        #pragma unroll
        for (int pt = 0; pt < 6; ++pt) {
            f16x8 wh = w2vh[(pt * 8 + kb) * 64 + l];       // 1 KB coalesced (L2)
            f16x8 wl = w2vl[(pt * 8 + kb) * 64 + l];
            #pragma unroll
            for (int mt = 0; mt < 2; ++mt) {
                acc2[pt][mt] = __builtin_amdgcn_mfma_f32_16x16x32_f16(wl, bh[mt], acc2[pt][mt], 0, 0, 0);
                acc2[pt][mt] = __builtin_amdgcn_mfma_f32_16x16x32_f16(wh, bl[mt], acc2[pt][mt], 0, 0, 0);
                acc2[pt][mt] = __builtin_amdgcn_mfma_f32_16x16x32_f16(wh, bh[mt], acc2[pt][mt], 0, 0, 0);
            }
        }
    }

    // ---- spline: TWO sub-rounds of 16 rows, wave-private LDS, no barriers --
    // acc2[pt][rd] holds P[p][row = rd*16 + lc]; scratch is 16x97 per wave,
    // reusing the (now dead) xh/xl staging region.
    const int krow  = l & 15;          // knot row
    const int kset  = (l >> 4) & 1;    // 0 = widths (cols 0..31), 1 = heights (32..63)
    const int khalf = l >> 5;          // 0: entries 0..15, 1: entries 16..31

    #pragma unroll
    for (int rd = 0; rd < 2; ++rd) {
        // write P[r][p] = (acc2 + b2)*eta ; r = lc, p = pt*16+q*4
        #pragma unroll
        for (int pt = 0; pt < 6; ++pt) {
            float4 bb = *(const float4*)(sB2 + pt * 16 + q * 4);
            f32x4 v = acc2[pt][rd];
            float* dst = sPw + lc * 97 + pt * 16 + q * 4;
            dst[0] = (v[0] + bb.x) * ev;
            dst[1] = (v[1] + bb.y) * ev;
            dst[2] = (v[2] + bb.z) * ev;
            dst[3] = (v[3] + bb.w) * ev;
        }
        // knots: 64 lanes = 16 rows x {w,h} x 2 halves. Order-exact split:
        //   max: tree (fmax exactly associative -> bit-identical)
        //   cumsum: upper half restarts serial chain from lower half's c15
        //   S = upper half's final c (exact reference association)
        {
            float* basep = sPw + krow * 97 + kset * 32 + khalf * 16;
            float tv[16];
            #pragma unroll
            for (int j = 0; j < 16; ++j) tv[j] = basep[j];
            float mx = tv[0];
            #pragma unroll
            for (int j = 1; j < 16; ++j) mx = fmaxf(mx, tv[j]);
            mx = fmaxf(mx, __shfl_xor(mx, 32));
            // exps + local serial sum (half0's sum == exact c15)
            float cl = 0.f;
            #pragma unroll
            for (int j = 0; j < 16; ++j) {
                tv[j] = __expf(tv[j] - mx);
                cl += tv[j];
            }
            float cpart = __shfl_xor(cl, 32);      // half1 receives half0's c15
            // serial cumsum, order-exact: half0 from 0, half1 from c15
            float c = khalf ? cpart : 0.f;
            #pragma unroll
            for (int j = 0; j < 16; ++j) {
                c += tv[j];
                tv[j] = c;
            }
            float Sx = __shfl_xor(c, 32);          // half0 receives half1's c31 (=S)
            float S = khalf ? c : Sx;
            float scale = (1.0f - 32.0f * MIN_SZ) / S;
            float base_off = MIN_SZ * (float)(khalf * 16 + 1);
            #pragma unroll
            for (int j = 0; j < 16; ++j)
                basep[j] = TWO_PI_F * fmaf(scale, tv[j], base_off + MIN_SZ * (float)j);
            if (khalf) basep[15] = TWO_PI_F;       // knot_32 = right boundary
        }
        // eval + store: lanes 0..15 (one per row)
        if (l < 16) {
            const float* row = sPw + l * 97;
            long gr = R0w + rd * 16 + l;
            float th_in = rd ? th1 : th0;
            int bin = 0;
            #pragma unroll
            for (int j = 0; j < 32; ++j) bin += (th_in >= row[j]) ? 1 : 0;
            bin = min(bin, 31);

            float cwk1 = row[bin];
            float cwk0 = (bin == 0) ? 0.f : row[bin - 1];
            float chk1 = row[32 + bin];
            float chk0 = (bin == 0) ? 0.f : row[32 + bin - 1];
            float in_w = cwk1 - cwk0;
            float in_h = chk1 - chk0;
            float d_k  = MIN_D_F + softplus_f(row[64 + bin] + DERIV_OFF);
            float d_k1 = MIN_D_F + softplus_f(row[64 + ((bin + 1) & 31)] + DERIV_OFF);

            float s   = in_h / in_w;
            float tt  = (th_in - cwk0) / in_w;
            float tom = tt * (1.f - tt);
            float denom = s + (d_k1 + d_k - 2.f * s) * tom;
            float numer = in_h * (s * tt * tt + d_k * tom);
            float outv  = chk0 + numer / denom;
            float omt   = 1.f - tt;
            float dnum  = s * s * (d_k1 * tt * tt + 2.f * s * tom + d_k * omt * omt);
            float lad   = __logf(dnum) - 2.f * __logf(denom);

            out[gr]               = outv;
            out[(long)Btot + gr]  = lad;
        }
    }
}

extern "C" void kernel_launch(void* const* d_in, const int* in_sizes, int n_in,
                              void* d_out, int out_size, void* d_ws, size_t ws_size,
                              hipStream_t stream) {
    const float* theta = (const float*)d_in[0];
    const float* xcond = (const float*)d_in[1];
    const float* W1    = (const float*)d_in[2];
    const float* b1    = (const float*)d_in[3];
    const float* W2    = (const float*)d_in[4];
    const float* b2    = (const float*)d_in[5];
    const float* eta   = (const float*)d_in[6];
    int Btot = in_sizes[0];                    // 1048576 (d = 1)

    _Float16* w1h = (_Float16*)d_ws;           // 16384 f16
    _Float16* w1l = w1h + 16384;
    _Float16* w2h = w1l + 16384;               // 24576 f16
    _Float16* w2l = w2h + 24576;               // total 160 KiB of ws

    flow_prep<<<160, 256, 0, stream>>>(W1, W2, w1h, w1l, w2h, w2l);
    // 32 rows per wave, 4 waves per block -> 128 rows/block
    flow_main<<<Btot / 128, 256, 0, stream>>>(theta, xcond, b1, b2, eta,
                                              w1h, w1l, w2h, w2l,
                                              (float*)d_out, Btot);
}